// Round 10
// baseline (189.375 us; speedup 1.0000x reference)
//
#include <hip/hip_runtime.h>
#include <cmath>

#define IMG_H 4096
#define IMG_W 4096
#define GX 64
#define GY 64
#define WCOLS 64             /* output cols per wave = per block (1 col/lane) */
#define R 64                 /* output rows per block */
#define NITER (R + 10)       /* 74 h-rows per strip */
#define NQIT 19              /* quad-iterations (76 rows; last 2 clamped, guarded) */
#define SW 80                /* staged words per img per row */
#define RWORDS (2*SW)        /* 160 words per row (img1 then img2) */
#define NBUF 8               /* LDS ring: quads double-buffer (slots 0-3 / 4-7) */

struct GW { float w[11]; };

__device__ __forceinline__ int clampi(int v, int lo, int hi) {
  return v < lo ? lo : (v > hi ? hi : v);
}

// Round 10: quad-row iterations + 1-wave blocks.
// Round-9 post-mortem: double-row delivered (95.5->84 us, VALU ~74%);
// per-row VALU-issue is the currency. Occupancy pinned ~30% (~10 waves/CU)
// across r7/r8/r9 regardless of supply/granularity -> still probing.
// This round: (1) 4 rows/iter -- stage addressing, vmcnt, ring select,
// patch, loop control amortize /4; 16 independent h-chains for ILP; fused
// 4-absorb shift keeps 11 fma/row vertical. NBUF=8: write slots 4..7 while
// reading 0..3 (clean quad double-buffer), vmcnt(4) = 1 quad in flight.
// (2) 1-wave 64-thread blocks, 4096 blocks: finest dispatch granularity
// (tests the ~10 waves/CU residency cap), no end barrier/LDS reduction.
// SSIM folded per-row (o liveness 4, not 16); launch_bounds(64,3) cap 85.
// Lessons kept: wave-private LDS staging (r2/r6), global_load_lds w=16
// ring + counted vmcnt (r4/r7), rolled loop + shift register (r5),
// 1 col/lane (r7), multi-row amortization (r9), 4-channel algebra.
__global__ __launch_bounds__(64, 3) void ssim_sweep_kernel(
    const float* __restrict__ img1, const float* __restrict__ img2,
    float* __restrict__ partial, GW gw) {
  __shared__ __align__(16) float sbuf[NBUF][RWORDS];  // 5120 B

  const int lane = threadIdx.x;
  const int bx = blockIdx.x, by = blockIdx.y;
  const int cw   = bx * WCOLS;                // this block's first output col
  const int row0 = by * R;
  const bool ledge = (bx == 0), redge = (bx == GX - 1);

  // DMA map: one call, lanes 0..39 active; HW writes LDS base + 16*laneid.
  // lanes 0..19  -> img1 words 0..79   (cols [cw-8, cw+72))
  // lanes 20..39 -> img2 words 80..159
  const float* srcp = (lane < 20) ? img1 : img2;
  const int    co   = clampi(cw - 8 + 4 * ((lane < 20) ? lane : lane - 20),
                             0, IMG_W - 4);   // 16B-aligned (cw%64==0)

  auto stage = [&](int slot, int i) {
    const int gr = clampi(row0 - 5 + i, 0, IMG_H - 1);
    const long rb = (long)gr * IMG_W;
    float* dst = &sbuf[slot][0];
    if (lane < 40) {
      __builtin_amdgcn_global_load_lds(
          (const __attribute__((address_space(1))) void*)(srcp + rb + co),
          (__attribute__((address_space(3))) void*)dst, 16, 0, 0);
    }
  };

  // ---- prologue: rows 0..3 in flight ----
  stage(0, 0); stage(1, 1); stage(2, 2); stage(3, 3);

  // shift-register accumulator: A[ch][k], k=0..10; 1 col per lane.
  float A[4][11];
  float sum = 0.f;
  const float C1 = 6.5025f, C2 = 58.5225f;
  const int wl = lane + 3;   // first window word (col cw+lane, taps -5..+5)

  #pragma unroll 1
  for (int t = 0; t < NQIT; ++t) {
    const int i = 4 * t;

    // issue rows i+4..i+7 into the slot-half not being read this iter
    stage((i + 4) & 7, i + 4);
    stage((i + 5) & 7, i + 5);
    stage((i + 6) & 7, i + 6);
    stage((i + 7) & 7, i + 7);

    // counted wait: the 4 just-issued stay in flight; rows i..i+3 landed
    asm volatile("s_waitcnt vmcnt(4)" ::: "memory");
    __builtin_amdgcn_sched_barrier(0);

    float* buf0 = &sbuf[(i + 0) & 7][0];
    float* buf1 = &sbuf[(i + 1) & 7][0];
    float* buf2 = &sbuf[(i + 2) & 7][0];
    float* buf3 = &sbuf[(i + 3) & 7][0];

    // replicate-pad patch (edge blocks only): 64 lanes cover 4 bufs x 2
    // imgs x 8 words exactly
    if (ledge || redge) {
      const int bsel = lane >> 4;          // buffer 0..3
      const int im   = (lane >> 3) & 1;    // image half
      const int l    = lane & 7;
      float* bp = &sbuf[(i + bsel) & 7][0];
      const int srcw = im * SW + (ledge ? 8 : 71);
      const int dstw = im * SW + (ledge ? l : 72 + l);
      bp[dstw] = bp[srcw];
    }

    // fused 4-channel horizontal conv, 4 rows (16 independent chains)
    float h[4][4];  // [row][ch]
    #pragma unroll
    for (int r = 0; r < 4; ++r)
      #pragma unroll
      for (int ch = 0; ch < 4; ++ch) h[r][ch] = 0.f;
    #pragma unroll
    for (int j = 0; j <= 10; ++j) {
      const float w = gw.w[j];
      float* bufs[4] = {buf0, buf1, buf2, buf3};
      #pragma unroll
      for (int r = 0; r < 4; ++r) {
        const float a = bufs[r][wl + j];
        const float b = bufs[r][SW + wl + j];
        const float sq = fmaf(b, b, a * a);
        const float ab = a * b;
        h[r][0] = fmaf(w, a,  h[r][0]);
        h[r][1] = fmaf(w, b,  h[r][1]);
        h[r][2] = fmaf(w, sq, h[r][2]);
        h[r][3] = fmaf(w, ab, h[r][3]);
      }
    }

    // outputs for rows e=i-10..i-7 (read OLD A only), SSIM folded per row
    #pragma unroll
    for (int r = 0; r < 4; ++r) {
      const int e = i - 10 + r;           // wave-uniform
      if (e >= 0 && e < R) {
        float o[4];
        #pragma unroll
        for (int ch = 0; ch < 4; ++ch) {
          float v = A[ch][r + 1];
          #pragma unroll
          for (int q = 0; q <= r; ++q)    // taps w[10-r+q] on h[q][ch]
            v = fmaf(gw.w[10 - r + q], h[q][ch], v);
          o[ch] = v;
        }
        const float mu1 = o[0], mu2 = o[1], s3v = o[2], s4v = o[3];
        const float mu1s = mu1 * mu1, mu2s = mu2 * mu2, m12 = mu1 * mu2;
        const float num = (2.f * m12 + C1) * (2.f * (s4v - m12) + C2);
        const float den = (mu1s + mu2s + C1) * ((s3v - mu1s - mu2s) + C2);
        sum += num * __builtin_amdgcn_rcpf(den);
      }
    }

    // fused 4-absorb shift: A[k] = sum_q w[10-k-3+q]*h[q] + A[k+4]
    #pragma unroll
    for (int ch = 0; ch < 4; ++ch) {
      #pragma unroll
      for (int k = 0; k < 7; ++k)   // ascending: A[k+4] read before write
        A[ch][k] = fmaf(gw.w[10 - k], h[3][ch],
                   fmaf(gw.w[9 - k],  h[2][ch],
                   fmaf(gw.w[8 - k],  h[1][ch],
                   fmaf(gw.w[7 - k],  h[0][ch], A[ch][k + 4]))));
      A[ch][7]  = fmaf(gw.w[3], h[3][ch],
                  fmaf(gw.w[2], h[2][ch],
                  fmaf(gw.w[1], h[1][ch], gw.w[0] * h[0][ch])));
      A[ch][8]  = fmaf(gw.w[2], h[3][ch],
                  fmaf(gw.w[1], h[2][ch], gw.w[0] * h[1][ch]));
      A[ch][9]  = fmaf(gw.w[1], h[3][ch], gw.w[0] * h[2][ch]);
      A[ch][10] = gw.w[0] * h[3][ch];
    }
  }

  // ---- wave reduction (1 wave per block, no barrier) ----
  #pragma unroll
  for (int off = 32; off > 0; off >>= 1) sum += __shfl_down(sum, off);
  if (lane == 0) partial[by * GX + bx] = sum;
}

__global__ __launch_bounds__(256) void ssim_reduce_kernel(
    const float* __restrict__ partial, float* __restrict__ out) {
  int tid = threadIdx.x;
  // 4096 partials (GX*GY)
  double s = 0.0;
  #pragma unroll
  for (int k = 0; k < 16; ++k) s += (double)partial[tid + 256 * k];
  #pragma unroll
  for (int off = 32; off > 0; off >>= 1) s += __shfl_down(s, off);
  __shared__ double ws[4];
  if ((tid & 63) == 0) ws[tid >> 6] = s;
  __syncthreads();
  if (tid == 0)
    out[0] = (float)((ws[0] + ws[1] + ws[2] + ws[3]) /
                     ((double)IMG_H * (double)IMG_W));
}

extern "C" void kernel_launch(void* const* d_in, const int* in_sizes, int n_in,
                              void* d_out, int out_size, void* d_ws, size_t ws_size,
                              hipStream_t stream) {
  const float* img1 = (const float*)d_in[0];
  const float* img2 = (const float*)d_in[1];
  float* partial = (float*)d_ws;
  float* out = (float*)d_out;

  GW gw;
  double g[11], s = 0.0;
  for (int i = 0; i < 11; ++i) {
    double x = i - 5.0;
    g[i] = exp(-(x * x) / (2.0 * 1.5 * 1.5));
    s += g[i];
  }
  for (int i = 0; i < 11; ++i) gw.w[i] = (float)(g[i] / s);

  dim3 grid(GX, GY);
  ssim_sweep_kernel<<<grid, 64, 0, stream>>>(img1, img2, partial, gw);
  ssim_reduce_kernel<<<1, 256, 0, stream>>>(partial, out);
}

// Round 12
// 183.072 us; speedup vs baseline: 1.0344x; 1.0344x over previous
//
#include <hip/hip_runtime.h>
#include <cmath>

#define IMG_H 4096
#define IMG_W 4096
#define GX 32
#define GY 64
#define TCOLS 128            /* output cols per block (2 waves x 64) */
#define WCOLS 64             /* output cols per wave (1 col per lane) */
#define R 64                 /* output rows per block */
#define NITER (R + 10)       /* 74 h-rows per strip */
#define NDIT (NITER / 2)     /* 37 double-iterations */
#define SW 80                /* staged words per img per row */
#define RWORDS (2*SW)        /* 160 words per wave-row (img1 then img2) */
#define NBUF 4               /* LDS ring depth (rows i..i+3) */
#define NWV 2                /* waves per block */

struct GW { float w[11]; };

typedef float f2 __attribute__((ext_vector_type(2)));

__device__ __forceinline__ f2 pkfma(f2 a, f2 b, f2 c) {
  return __builtin_elementwise_fma(a, b, c);   // -> v_pk_fma_f32 on gfx950
}
__device__ __forceinline__ f2 spl(float w) { f2 r; r.x = w; r.y = w; return r; }

__device__ __forceinline__ int clampi(int v, int lo, int hi) {
  return v < lo ? lo : (v > hi ? hi : v);
}

// Round 12: VERBATIM resubmit of round 11 (container failed twice; rounds
// 3 and 6 failed identically and both cleared on verbatim resubmit ->
// infra flake). New surface vs r9 (HW-passed) is pure value arithmetic
// (f2 ext_vector + elementwise_fma); staging/DMA/vmcnt skeleton is
// byte-identical to r9's proven one.
//
// Round 11: r9 skeleton + channel-pair packed FP32 (v_pk_fma_f32).
// Round-10 post-mortem: quad-row REGRESSED (84->93.5): 64-col blocks
// over-fetch (FETCH 129->162 MB), 1-wave blocks dropped occupancy to 24%,
// o-chain triangular taps grew VALU 62->71 us. Revert to r9 shape.
// This round: gfx950 fp32 peak (157 TF) is 2x the scalar VALU issue rate
// (78.6 TF) -- the 2x is VOP3P v_pk_fma_f32. Kernel is issue-bound
// (VALU 74%, occupancy reg-capped ~30%). Pack by CHANNEL PAIRS:
// {mu1,mu2} accumulates vs m={a,b}; {s3,s4} vs {sq,ab}; vertical shift
// wholly packed (88 fma -> 44 pk_fma per double-iter); h outputs are
// already channel-paired so no repacking anywhere. ext_vector float2 +
// __builtin_elementwise_fma (lowered to pk on packed-fp32 targets;
// harmless scalarization otherwise). Static arith/double-iter 224 -> 146.
// Lessons kept: wave-private LDS, no main-loop barriers (r2), w=16
// global_load_lds ring + counted vmcnt(2) (r4/r7), rolled loop + shift
// register (r5), 1 col/lane (r7), double-row amortization (r9),
// 2-wave blocks TCOLS=128 (r9/r10), 4-channel algebra.
__global__ __launch_bounds__(128, 3) void ssim_sweep_kernel(
    const float* __restrict__ img1, const float* __restrict__ img2,
    float* __restrict__ partial, GW gw) {
  __shared__ __align__(16) float sbuf[NWV][NBUF][RWORDS];  // 5120 B

  const int tid  = threadIdx.x;
  const int wv   = tid >> 6;
  const int lane = tid & 63;
  const int bx = blockIdx.x, by = blockIdx.y;
  const int cw   = bx * TCOLS + wv * WCOLS;   // this wave's first output col
  const int row0 = by * R;
  const bool ledge = (cw == 0), redge = (cw + WCOLS == IMG_W);

  // DMA map: one call, lanes 0..39 active; HW writes LDS base + 16*laneid.
  // lanes 0..19  -> img1 words 0..79   (cols [cw-8, cw+72))
  // lanes 20..39 -> img2 words 80..159
  const float* srcp = (lane < 20) ? img1 : img2;
  const int    co   = clampi(cw - 8 + 4 * ((lane < 20) ? lane : lane - 20),
                             0, IMG_W - 4);   // 16B-aligned (cw%64==0)

  float* swv = &sbuf[wv][0][0];

  auto stage = [&](int slot, int i) {
    const int gr = clampi(row0 - 5 + i, 0, IMG_H - 1);
    const long rb = (long)gr * IMG_W;
    float* dst = swv + slot * RWORDS;
    if (lane < 40) {
      __builtin_amdgcn_global_load_lds(
          (const __attribute__((address_space(1))) void*)(srcp + rb + co),
          (__attribute__((address_space(3))) void*)dst, 16, 0, 0);
    }
  };

  // ---- prologue: rows 0,1 in flight ----
  stage(0, 0);
  stage(1, 1);

  // channel-pair shift registers: Am[k]={mu1,mu2}, As[k]={s3,s4}, k=0..10
  f2 Am[11], As[11];
  float sum = 0.f;
  const float C1 = 6.5025f, C2 = 58.5225f;
  const int wl = lane + 3;   // first window word (col cw+lane, taps -5..+5)

  #pragma unroll 1
  for (int t = 0; t < NDIT; ++t) {
    const int i = 2 * t;
    const int s0 = i & 3, s1 = (i + 1) & 3, s2 = (i + 2) & 3, s3 = (i + 3) & 3;

    // issue rows i+2, i+3 into the slots consumed at iter t-1
    // (tail: clamped re-reads into dead slots -- harmless, branch-free)
    stage(s2, i + 2);
    stage(s3, i + 3);

    // counted wait: the 2 just-issued ops stay in flight; rows i,i+1 landed
    asm volatile("s_waitcnt vmcnt(2)" ::: "memory");
    __builtin_amdgcn_sched_barrier(0);

    float* buf0 = swv + s0 * RWORDS;
    float* buf1 = swv + s1 * RWORDS;

    // replicate-pad patch (edge waves only): 32 lanes patch both buffers
    if (ledge || redge) {
      if (lane < 32) {
        const int bsel = lane >> 4;          // 0: buf0, 1: buf1
        const int im   = (lane >> 3) & 1;    // image half
        const int l    = lane & 7;
        float* bp = bsel ? buf1 : buf0;
        const int srcw = im * SW + (ledge ? 8 : 71);
        const int dstw = im * SW + (ledge ? l : 72 + l);
        bp[dstw] = bp[srcw];
      }
    }

    // fused packed horizontal conv, both rows (independent chains)
    f2 hm0 = {0.f, 0.f}, hs0 = {0.f, 0.f};
    f2 hm1 = {0.f, 0.f}, hs1 = {0.f, 0.f};
    #pragma unroll
    for (int j = 0; j <= 10; ++j) {
      const f2 w2 = spl(gw.w[j]);
      {
        const float a = buf0[wl + j], b = buf0[SW + wl + j];
        f2 m; m.x = a; m.y = b;
        f2 s; s.x = fmaf(b, b, a * a); s.y = a * b;
        hm0 = pkfma(w2, m, hm0);
        hs0 = pkfma(w2, s, hs0);
      }
      {
        const float a = buf1[wl + j], b = buf1[SW + wl + j];
        f2 m; m.x = a; m.y = b;
        f2 s; s.x = fmaf(b, b, a * a); s.y = a * b;
        hm1 = pkfma(w2, m, hm1);
        hs1 = pkfma(w2, s, hs1);
      }
    }

    // row i-10 output (reads OLD Am/As[1] before the update)
    const f2 o0m = pkfma(spl(gw.w[10]), hm0, Am[1]);
    const f2 o0s = pkfma(spl(gw.w[10]), hs0, As[1]);

    // fused packed double shift: A[k] = w[10-k]*h1 + w[9-k]*h0 + A[k+2]
    #pragma unroll
    for (int k = 0; k < 9; ++k) {   // ascending: A[k+2] read before write
      Am[k] = pkfma(spl(gw.w[10 - k]), hm1, pkfma(spl(gw.w[9 - k]), hm0, Am[k + 2]));
      As[k] = pkfma(spl(gw.w[10 - k]), hs1, pkfma(spl(gw.w[9 - k]), hs0, As[k + 2]));
    }
    Am[9]  = pkfma(spl(gw.w[1]), hm1, spl(gw.w[0]) * hm0);
    As[9]  = pkfma(spl(gw.w[1]), hs1, spl(gw.w[0]) * hs0);
    Am[10] = spl(gw.w[0]) * hm1;
    As[10] = spl(gw.w[0]) * hs1;

    // rows i-10 (o0) and i-9 (A[0] post-update) -> SSIM + sum
    if (i >= 10) {
      {
        const float mu1 = o0m.x, mu2 = o0m.y, s3v = o0s.x, s4v = o0s.y;
        const float mu1s = mu1 * mu1, mu2s = mu2 * mu2, m12 = mu1 * mu2;
        const float num = (2.f * m12 + C1) * (2.f * (s4v - m12) + C2);
        const float den = (mu1s + mu2s + C1) * ((s3v - mu1s - mu2s) + C2);
        sum += num * __builtin_amdgcn_rcpf(den);
      }
      {
        const float mu1 = Am[0].x, mu2 = Am[0].y, s3v = As[0].x, s4v = As[0].y;
        const float mu1s = mu1 * mu1, mu2s = mu2 * mu2, m12 = mu1 * mu2;
        const float num = (2.f * m12 + C1) * (2.f * (s4v - m12) + C2);
        const float den = (mu1s + mu2s + C1) * ((s3v - mu1s - mu2s) + C2);
        sum += num * __builtin_amdgcn_rcpf(den);
      }
    }
  }

  // ---- block reduction (single barrier, end of kernel) ----
  #pragma unroll
  for (int off = 32; off > 0; off >>= 1) sum += __shfl_down(sum, off);
  __shared__ float wsum[NWV];
  if (lane == 0) wsum[wv] = sum;
  __syncthreads();
  if (tid == 0)
    partial[by * GX + bx] = wsum[0] + wsum[1];
}

__global__ __launch_bounds__(256) void ssim_reduce_kernel(
    const float* __restrict__ partial, float* __restrict__ out) {
  int tid = threadIdx.x;
  // 2048 partials (GX*GY)
  double s = 0.0;
  #pragma unroll
  for (int k = 0; k < 8; ++k) s += (double)partial[tid + 256 * k];
  #pragma unroll
  for (int off = 32; off > 0; off >>= 1) s += __shfl_down(s, off);
  __shared__ double ws[4];
  if ((tid & 63) == 0) ws[tid >> 6] = s;
  __syncthreads();
  if (tid == 0)
    out[0] = (float)((ws[0] + ws[1] + ws[2] + ws[3]) /
                     ((double)IMG_H * (double)IMG_W));
}

extern "C" void kernel_launch(void* const* d_in, const int* in_sizes, int n_in,
                              void* d_out, int out_size, void* d_ws, size_t ws_size,
                              hipStream_t stream) {
  const float* img1 = (const float*)d_in[0];
  const float* img2 = (const float*)d_in[1];
  float* partial = (float*)d_ws;
  float* out = (float*)d_out;

  GW gw;
  double g[11], s = 0.0;
  for (int i = 0; i < 11; ++i) {
    double x = i - 5.0;
    g[i] = exp(-(x * x) / (2.0 * 1.5 * 1.5));
    s += g[i];
  }
  for (int i = 0; i < 11; ++i) gw.w[i] = (float)(g[i] / s);

  dim3 grid(GX, GY);
  ssim_sweep_kernel<<<grid, 128, 0, stream>>>(img1, img2, partial, gw);
  ssim_reduce_kernel<<<1, 256, 0, stream>>>(partial, out);
}